// Round 12
// baseline (1536.630 us; speedup 1.0000x reference)
//
#include <hip/hip_runtime.h>

#define BB 8
#define NN 8192
#define MM 512
#define KK 6
#define NSAMP 16
#define CC 13
#define DD 64

typedef float v2f __attribute__((ext_vector_type(2)));

// ---- output slot offsets (in floats) ----
#define O_ASSO   0u          // final_asso      (B,N,K)  393216
#define O_CIDX   393216u     // cluster_idx     (B,M)    4096
#define O_C2P    397312u     // c2p_idx         (B,N,K)  393216
#define O_C2PA   790528u     // c2p_idx_abs     (B,N,K)  393216
#define O_OUT    1183744u    // out             (B,N,C)  851968
#define O_RPXYZ  2035712u    // re_p_xyz        (B,N,3)  196608
#define O_RPLAB  2232320u    // re_p_label      (B,N,C)  851968
#define O_FDIST  3084288u    // fea_dist        (B,N,K)  393216
#define O_PFEA   3477504u    // p_fea           (B,N,D)  4194304
#define O_SPLABT 7671808u    // sp_label^T      (B,C,M)  53248
#define O_PSLAB  7725056u    // sp_pseudo_lab   (B,M)    4096
#define O_PSOH   7729152u    // sp_pseudo_oh    (B,C,M)  53248

// ---- wave64 DPP max-reduce of a u64 key; valid result in lane 63 ----
// bound_ctrl 0-fill safe: every live key has nonzero low word (ck != 0),
// and high word = non-negative f32 bits, so a 0-filled neighbor never wins.
__device__ __forceinline__ unsigned long long dpp_max_u64(unsigned long long k) {
  int lo = (int)(unsigned)(k & 0xFFFFFFFFull);
  int hi = (int)(unsigned)(k >> 32);
#define DPP_STEP(ctrl)                                                         \
  {                                                                            \
    int nlo = __builtin_amdgcn_update_dpp(0, lo, ctrl, 0xf, 0xf, true);        \
    int nhi = __builtin_amdgcn_update_dpp(0, hi, ctrl, 0xf, 0xf, true);        \
    unsigned long long nk =                                                    \
        ((unsigned long long)(unsigned)nhi << 32) | (unsigned)nlo;             \
    unsigned long long ck =                                                    \
        ((unsigned long long)(unsigned)hi << 32) | (unsigned)lo;               \
    if (nk > ck) { lo = nlo; hi = nhi; }                                       \
  }
  DPP_STEP(0x111)  // row_shr:1
  DPP_STEP(0x112)  // row_shr:2
  DPP_STEP(0x114)  // row_shr:4
  DPP_STEP(0x118)  // row_shr:8  -> lane15/31/47/63 hold row maxima
  DPP_STEP(0x142)  // row_bcast:15 -> lane31=max(r0,r1), lane63=max(r2,r3)
  DPP_STEP(0x143)  // row_bcast:31 -> lane63=max(all)
#undef DPP_STEP
  return ((unsigned long long)(unsigned)hi << 32) | (unsigned)lo;
}

// ================= FPS: one 256-thread block per batch, 32 pts/thread ============
// STANDALONE kernel — do NOT fuse other work into this kernel (R1 post-mortem:
// shared register allocation poisons the co-resident path; 25x slowdown).
// R5 post-mortem: keep selection on ONE barrier (two-barrier split regressed).
// R11 post-mortem: halving issue (8w->4w) left duration unchanged -> the step
// is SERIAL-CHAIN-bound, not issue-bound. R12 attacks the chain:
//  - tree-resolve: per-slot candidate key (dist==vbest ? 0xFFFFFFFF-p : 0),
//    depth-5 max tree (~25 cyc chain) replaces the 32-deep sequential cndmask
//    scan (~128 cyc). max-of-keys == min-p-of-matches == old first-match rule.
//  - single u64 DPP ladder on (vbest_bits<<32)|ck (~90 cyc chain) replaces
//    f32 ladder -> readlane -> u32 ladder (~140 cyc serialized through wmax).
//    Lexicographic u64 max == (max vbest, then min p): identical winner;
//    non-negative f32 bits are order-isomorphic to u32. Bit-exact.
// p = t + (2j+s)*256 keeps the ascending-p property; distance math unchanged
// (contract off); min/max exact -> bit-exact selection sequence.
// waves_per_eu(1,1) + launch_bounds(256,1): ~128 VGPR of point state must
// stay resident (session failure mode #1). Health check: VGPR >= 130.
__attribute__((amdgpu_waves_per_eu(1, 1)))
__global__ __launch_bounds__(256, 1) void k_fps(const float* __restrict__ pc,
                                                int* __restrict__ cidx,
                                                float* __restrict__ cxyz,
                                                float* __restrict__ out) {
#pragma clang fp contract(off)
  __shared__ float4 sxyzw[NN];                 // 128 KB
  __shared__ unsigned long long s_best[2][4];
  __shared__ int s_pidx[MM];
  const int t = threadIdx.x;                   // 0..255
  const int b = blockIdx.x;
  const float* xb = pc + (size_t)b * NN * 6;
  v2f px[16], py[16], pz[16], dist[16];
#pragma unroll
  for (int j = 0; j < 16; ++j) {
    int p0 = t + (2*j)*256, p1 = t + (2*j+1)*256;
    float X0 = xb[(size_t)p0*6+0], Y0 = xb[(size_t)p0*6+1], Z0 = xb[(size_t)p0*6+2];
    float X1 = xb[(size_t)p1*6+0], Y1 = xb[(size_t)p1*6+1], Z1 = xb[(size_t)p1*6+2];
    px[j] = (v2f){X0, X1}; py[j] = (v2f){Y0, Y1}; pz[j] = (v2f){Z0, Z1};
    dist[j] = (v2f){1e10f, 1e10f};
    sxyzw[p0] = make_float4(X0, Y0, Z0, 0.f);
    sxyzw[p1] = make_float4(X1, Y1, Z1, 0.f);
  }
  __syncthreads();
  float4 cv = sxyzw[0];
  float lx = cv.x, ly = cv.y, lz = cv.z;
  if (t == 0) s_pidx[0] = 0;
  const int lane = t & 63, wave = t >> 6;      // wave 0..3
  for (int step = 1; step < MM; ++step) {
    v2f vmax2 = (v2f){-1.0f, -1.0f};
#pragma unroll
    for (int j = 0; j < 16; ++j) {
      v2f dx = px[j] - lx, dy = py[j] - ly, dz = pz[j] - lz;
      v2f d = (dx*dx + dy*dy) + dz*dz;       // contract(off): exact numpy order
      v2f nd = __builtin_elementwise_min(dist[j], d);
      dist[j] = nd;
      vmax2 = __builtin_elementwise_max(vmax2, nd);
    }
    float vbest = fmaxf(vmax2.x, vmax2.y);
    // tree-resolve: ck = max over matching slots of (0xFFFFFFFF - p)
    // (== 0xFFFFFFFF - min matching p; vbest is exactly one of the values)
    unsigned ck;
    {
      unsigned c16[16];
#pragma unroll
      for (int j = 0; j < 16; ++j) {
        unsigned kx = (dist[j].x == vbest)
                          ? (0xFFFFFFFFu - (unsigned)(t + ((2*j) << 8))) : 0u;
        unsigned ky = (dist[j].y == vbest)
                          ? (0xFFFFFFFFu - (unsigned)(t + ((2*j+1) << 8))) : 0u;
        c16[j] = (kx > ky) ? kx : ky;
      }
      unsigned c8[8];
#pragma unroll
      for (int j = 0; j < 8; ++j)
        c8[j] = (c16[2*j] > c16[2*j+1]) ? c16[2*j] : c16[2*j+1];
      unsigned c4[4];
#pragma unroll
      for (int j = 0; j < 4; ++j)
        c4[j] = (c8[2*j] > c8[2*j+1]) ? c8[2*j] : c8[2*j+1];
      unsigned ca = (c4[0] > c4[1]) ? c4[0] : c4[1];
      unsigned cb = (c4[2] > c4[3]) ? c4[2] : c4[3];
      ck = (ca > cb) ? ca : cb;
    }
    unsigned long long key =
        ((unsigned long long)__float_as_uint(vbest) << 32) | ck;
    key = dpp_max_u64(key);               // single ladder; lane 63 valid
    if (lane == 63) s_best[step & 1][wave] = key;
    __syncthreads();                      // single barrier (parity dbuf)
    const ulonglong2* sb = (const ulonglong2*)s_best[step & 1];
    ulonglong2 q0 = sb[0], q1 = sb[1];
    unsigned long long m0 = (q0.y > q0.x) ? q0.y : q0.x;   // depth-2 tree
    unsigned long long m1 = (q1.y > q1.x) ? q1.y : q1.x;
    unsigned long long kk = (m1 > m0) ? m1 : m0;
    int p = (int)(0xFFFFFFFFu - (unsigned)(kk & 0xFFFFFFFFull));
    float4 cp = sxyzw[p];                 // one b128 LDS broadcast
    lx = cp.x; ly = cp.y; lz = cp.z;
    if (t == 0) s_pidx[step] = p;
  }
  __syncthreads();
  // coalesced epilogue: 256 threads cover 512 selected entries
  for (int idx = t; idx < MM; idx += 256) {
    int p = s_pidx[idx];
    cidx[b*MM + idx] = p;
    out[O_CIDX + b*MM + idx] = (float)p;
    float4 cc = sxyzw[p];
    cxyz[((size_t)b*MM + idx)*3+0] = cc.x;
    cxyz[((size_t)b*MM + idx)*3+1] = cc.y;
    cxyz[((size_t)b*MM + idx)*3+2] = cc.z;
  }
}

// ================= pack + p_fea + head: 1 point/thread, no LDS ===================
// amdgpu_waves_per_eu(1,2): 256-VGPR budget so acc[64]+h1[32] stay in registers.
// (Do NOT change the attribute; do NOT fuse into k_fps — R1 post-mortem.)
__attribute__((amdgpu_waves_per_eu(1, 2)))
__global__ __launch_bounds__(256) void k_pfea(const float* __restrict__ pc,
                                              const float* __restrict__ knn,
                                              const float* __restrict__ Wk1,
                                              const float* __restrict__ Wk2,
                                              const float* __restrict__ Wg,
                                              const float* __restrict__ hW1,
                                              const float* __restrict__ hW2,
                                              float* __restrict__ xyz,
                                              float* __restrict__ out) {
  int i = blockIdx.x * 256 + threadIdx.x;
  const float2* pr = (const float2*)(pc + (size_t)i*6);
  float2 r0 = pr[0], r1 = pr[1], r2 = pr[2];
  float* xo = xyz + (size_t)i*3;
  xo[0] = r0.x; xo[1] = r0.y; xo[2] = r1.x;
  float acc[DD];
#pragma unroll
  for (int d = 0; d < DD; ++d) acc[d] = -3.4e38f;
  const float* kp = knn + (size_t)i * NSAMP * 2;
  for (int s = 0; s < NSAMP; ++s) {
    float u = kp[s*2+0], v2 = kp[s*2+1];
    float h1[32];
#pragma unroll
    for (int j = 0; j < 32; ++j) h1[j] = fmaxf(u*Wk1[j] + v2*Wk1[32+j], 0.f);
#pragma unroll
    for (int d = 0; d < DD; ++d) {
      float tt = 0.f;
#pragma unroll
      for (int j = 0; j < 32; ++j) tt += h1[j]*Wk2[j*DD+d];
      acc[d] = fmaxf(acc[d], tt);
    }
  }
  float f0 = r1.y, f1 = r2.x, f2 = r2.y;
#pragma unroll
  for (int d = 0; d < DD; ++d) {
    float hg = fmaxf(f0*Wg[d] + f1*Wg[DD+d] + f2*Wg[2*DD+d], 0.f);
    acc[d] = fmaxf(acc[d], 0.f) + hg;          // final p_fea value
    out[O_PFEA + (size_t)i*DD + d] = acc[d];
  }
  // fused head MLP: out = relu(p_fea @ hW1) @ hW2
  float o[CC];
#pragma unroll
  for (int c = 0; c < CC; ++c) o[c] = 0.f;
  for (int d = 0; d < DD; ++d) {
    float t1 = 0.f;
#pragma unroll
    for (int j = 0; j < DD; ++j) t1 += acc[j]*hW1[j*DD+d];
    t1 = fmaxf(t1, 0.f);
#pragma unroll
    for (int c = 0; c < CC; ++c) o[c] += t1*hW2[d*CC+c];
  }
#pragma unroll
  for (int c = 0; c < CC; ++c) out[O_OUT + (size_t)i*CC + c] = o[c];
}

// ---------------- 6-NN cluster search (stable top-k) ----------------
__global__ __launch_bounds__(256) void k_knn(const float* __restrict__ xyz,
                      const float* __restrict__ cxyz,
                      const int* __restrict__ cidx, int* __restrict__ c2p,
                      float* __restrict__ out) {
  __shared__ float4 sc[MM];
  int i = blockIdx.x * 256 + threadIdx.x;
  int b = i >> 13;
  for (int m = threadIdx.x; m < MM; m += 256) {
    sc[m] = make_float4(cxyz[((size_t)b*MM+m)*3+0], cxyz[((size_t)b*MM+m)*3+1],
                        cxyz[((size_t)b*MM+m)*3+2], 0.f);
  }
  __syncthreads();
  float x = xyz[(size_t)i*3+0], y = xyz[(size_t)i*3+1], z = xyz[(size_t)i*3+2];
  float dv[KK]; int di[KK];
#pragma unroll
  for (int j = 0; j < KK; ++j) { dv[j] = 3.4e38f; di[j] = 0; }
  for (int m = 0; m < MM; ++m) {
    float4 c = sc[m];
    float dx = x - c.x, dy = y - c.y, dz = z - c.z;
    float d = __fadd_rn(__fadd_rn(__fmul_rn(dx,dx), __fmul_rn(dy,dy)), __fmul_rn(dz,dz));
    if (d < dv[KK-1]) {
      float v = d; int vi = m; bool ins = false;
#pragma unroll
      for (int j = 0; j < KK; ++j) {
        bool doit = ins || (v < dv[j]);   // strict <: stable top_k
        float tv = doit ? dv[j] : v; int ti = doit ? di[j] : vi;
        if (doit) { dv[j] = v; di[j] = vi; }
        v = tv; vi = ti; ins = doit;
      }
    }
  }
#pragma unroll
  for (int k = 0; k < KK; ++k) {
    c2p[(size_t)i*KK+k] = di[k];
    out[O_C2PA + (size_t)i*KK + k] = (float)di[k];
    out[O_C2P  + (size_t)i*KK + k] = (float)cidx[b*MM + di[k]];
  }
}

// ---------------- fused CSR build + pseudo-label: one block per batch ----------
// R7 post-mortem: global-atomic CSR split (knn-fused count + scan + fill) was
// neutral (+14us) — this single-kernel form is equal or better and simpler.
__global__ __launch_bounds__(1024) void k_csr(const int* __restrict__ c2p,
                                              const int* __restrict__ label,
                                              int* __restrict__ cnt_g,
                                              int* __restrict__ offs_g,
                                              int* __restrict__ entries,
                                              float* __restrict__ out) {
  __shared__ int s_cnt[MM];
  __shared__ int s_off[MM];
  __shared__ int s_cur[MM];
  __shared__ int s_lab[MM*CC];
  int b = blockIdx.x, t = threadIdx.x;
  for (int i = t; i < MM; i += 1024) s_cnt[i] = 0;
  for (int i = t; i < MM*CC; i += 1024) s_lab[i] = 0;
  __syncthreads();
  const int* cb = c2p + (size_t)b*NN*KK;
  const int* lb = label + (size_t)b*NN;
  for (int n = t; n < NN; n += 1024) {
    int lab = lb[n];
#pragma unroll
    for (int k = 0; k < KK; ++k) {
      int m = cb[(size_t)n*KK+k];
      atomicAdd(&s_cnt[m], 1);
      atomicAdd(&s_lab[m*CC+lab], 1);
    }
  }
  __syncthreads();
  if (t < MM) s_off[t] = s_cnt[t];
  __syncthreads();
  for (int off = 1; off < MM; off <<= 1) {
    int v = 0;
    if (t < MM && t >= off) v = s_off[t-off];
    __syncthreads();
    if (t < MM && t >= off) s_off[t] += v;
    __syncthreads();
  }
  if (t < MM) {
    int ex = (t == 0) ? 0 : s_off[t-1];
    s_cur[t] = ex;
    offs_g[b*MM+t] = ex;
    cnt_g[b*MM+t] = s_cnt[t];
    int best = 0, bv = s_lab[t*CC];
#pragma unroll
    for (int c = 1; c < CC; ++c) { int v = s_lab[t*CC+c]; if (v > bv) { bv = v; best = c; } }
    out[O_PSLAB + b*MM + t] = (float)best;
#pragma unroll
    for (int c = 0; c < CC; ++c)
      out[O_PSOH + ((size_t)b*CC + c)*MM + t] = (c == best) ? 1.0f : 0.0f;
  }
  __syncthreads();
  for (int n = t; n < NN; n += 1024) {
#pragma unroll
    for (int k = 0; k < KK; ++k) {
      int m = cb[(size_t)n*KK+k];
      int pos = atomicAdd(&s_cur[m], 1);
      entries[(size_t)b*NN*KK + pos] = n*KK + k;
    }
  }
}

// ---------------- weighted scatter + fused sf@Wf1 (smeta) ----------------
// w==null     : init mode (w=1, sp_xyz=cxyz, den floor 1.0)
// onehot!=null: also produce sp_label (+ transposed output)
// Wf1n!=null  : produce smeta for the NEXT slic layer
// R5/R6 (measured ~-40us total): 2-deep load pipeline — entry e+4's loads
// issue before entry e is accumulated. Same FP order (bit-identical).
__global__ __launch_bounds__(256, 1) void k_scat(const float* __restrict__ pfea,
                          const float* __restrict__ xyz,
                          const float* __restrict__ w,
                          const float* __restrict__ cxyz,
                          const float* __restrict__ onehot,
                          const int* __restrict__ entries, const int* __restrict__ offs,
                          const int* __restrict__ cnt,
                          const float* __restrict__ Wf1n,
                          float* __restrict__ sp_fea, float* __restrict__ sp_xyz,
                          float* __restrict__ sp_label, float* __restrict__ smeta,
                          float* __restrict__ out) {
  int bm = blockIdx.x;
  int b = bm >> 9, m = bm & (MM-1);
  int t = threadIdx.x;
  int wv = t >> 6, lane = t & 63;
  int base = b*NN*KK;
  int st = offs[bm], n_e = cnt[bm];
  __shared__ int   s_ent[1024];
  __shared__ float s_w[1024];
  __shared__ float s_f[4][DD], s_x[4][4], s_l[4][16], s_d[4];
  __shared__ float s_sf[DD], s_part[16][17];
  float acc = 0.f, accx = 0.f, accl = 0.f, den = 0.f;
  for (int c0 = 0; c0 < n_e; c0 += 1024) {
    int cn = min(1024, n_e - c0);
    __syncthreads();
    for (int e = t; e < cn; e += 256) {
      int ee = entries[base + st + c0 + e];
      s_ent[e] = ee;
      s_w[e] = w ? w[(size_t)base + ee] : 1.0f;
    }
    __syncthreads();
    int e = wv;
    if (e < cn) {
      int ee = s_ent[e];
      float ww = s_w[e];
      int n = ee / KK;
      float pv = pfea[((size_t)b*NN+n)*DD + lane];
      float xv = (lane < 3) ? xyz[((size_t)b*NN+n)*3 + lane] : 0.f;
      float ov = (onehot && lane < CC) ? onehot[((size_t)b*NN+n)*CC + lane] : 0.f;
      for (; e + 4 < cn; e += 4) {
        int ee2 = s_ent[e+4];
        float ww2 = s_w[e+4];
        int n2 = ee2 / KK;
        float pv2 = pfea[((size_t)b*NN+n2)*DD + lane];
        float xv2 = (lane < 3) ? xyz[((size_t)b*NN+n2)*3 + lane] : 0.f;
        float ov2 = (onehot && lane < CC) ? onehot[((size_t)b*NN+n2)*CC + lane] : 0.f;
        acc += ww * pv;
        if (lane < 3) accx += ww * xv;
        if (onehot && lane < CC) accl += ww * ov;
        den += ww;
        ww = ww2; pv = pv2; xv = xv2; ov = ov2;
      }
      acc += ww * pv;
      if (lane < 3) accx += ww * xv;
      if (onehot && lane < CC) accl += ww * ov;
      den += ww;
    }
  }
  s_f[wv][lane] = acc;
  if (lane < 4)  s_x[wv][lane] = (lane < 3) ? accx : 0.f;
  if (lane < 16) s_l[wv][lane] = (lane < CC) ? accl : 0.f;
  if (lane == 0) s_d[wv] = den;
  __syncthreads();
  if (wv == 0) {
    float A  = s_f[0][lane] + s_f[1][lane] + s_f[2][lane] + s_f[3][lane];
    float Dn = s_d[0] + s_d[1] + s_d[2] + s_d[3];
    float dv = w ? fmaxf(Dn, 1e-8f) : fmaxf(Dn, 1.0f);
    float sfv = A / dv;
    sp_fea[(size_t)bm*DD + lane] = sfv;
    s_sf[lane] = sfv;
    if (lane < 3) {
      float X = w ? (s_x[0][lane]+s_x[1][lane]+s_x[2][lane]+s_x[3][lane]) / dv
                  : cxyz[bm*3+lane];
      sp_xyz[bm*3+lane] = X;
      if (Wf1n) smeta[bm*20 + 16 + lane] = X;
    }
    if (onehot && lane < CC) {
      float L = (s_l[0][lane]+s_l[1][lane]+s_l[2][lane]+s_l[3][lane]) / fmaxf(Dn, 1e-8f);
      sp_label[(size_t)bm*CC + lane] = L;
      out[O_SPLABT + ((size_t)b*CC + lane)*MM + m] = L;
    }
  }
  if (Wf1n) {
    __syncthreads();
    int c = t & 15, part = t >> 4;
    float pr = 0.f;
#pragma unroll
    for (int q = 0; q < 4; ++q)
      pr += s_sf[part*4+q] * Wf1n[(part*4+q)*16 + c];
    s_part[part][c] = pr;
    __syncthreads();
    if (t < 16) {
      float sm = 0.f;
#pragma unroll
      for (int q = 0; q < 16; ++q) sm += s_part[q][t];
      smeta[bm*20 + t] = sm;
    }
  }
}

// ---------------- SLIC weight computation (one iteration) ----------------
// (1,2): 256-VGPR budget; pf[64] + pipeline regs stay resident.
// R2 post-mortem: keep `#pragma unroll 1` on the k-loop (full unroll collapsed
// the allocation to 88 VGPR, pf[64] evicted, 5.5x slower at 1 wave/EU).
// R8 post-mortem: half-split 2x-TLP regressed (barriers + duplicated work).
// R9 post-mortem: LDS-staging smeta regressed (smeta is L2-resident; the
// rolled prefetch below already hides the gather latency; staging exposed it).
// R4 rolled-loop software pipeline (measured best): prologue hoists c2p[0] +
// k=0 smeta gather under the a/pm/pfd matmuls; each iteration issues c2p[k+1]
// at top and the next smeta gather mid-iteration into NAMED regs n0..n4
// (static indexing only), rotated at the bottom.
__attribute__((amdgpu_waves_per_eu(1, 2)))
__global__ __launch_bounds__(256) void k_slicw(const float* __restrict__ pfea,
                        const float* __restrict__ xyz,
                        const float* __restrict__ smeta,
                        const int* __restrict__ c2p,
                        const float* __restrict__ Wf1, const float* __restrict__ Wf2,
                        const float* __restrict__ Wx1, const float* __restrict__ Wx2,
                        const float* __restrict__ Wm1, const float* __restrict__ Wm2,
                        float* __restrict__ wout, float* __restrict__ wout2) {
  int i = blockIdx.x*256 + threadIdx.x;
  int b = i >> 13;
  const int* cpb = c2p + (size_t)i*KK;
  int mi0 = cpb[0];                       // issued early; hidden under a/pm
  float pf[DD];
  const float4* pf4 = (const float4*)(pfea + (size_t)i*DD);
#pragma unroll
  for (int q = 0; q < DD/4; ++q) {
    float4 t = pf4[q];
    pf[q*4+0] = t.x; pf[q*4+1] = t.y; pf[q*4+2] = t.z; pf[q*4+3] = t.w;
  }
  float a[16];
#pragma unroll
  for (int c = 0; c < 16; ++c) a[c] = 0.f;
#pragma unroll
  for (int d = 0; d < DD; ++d) {
    float f = pf[d];
#pragma unroll
    for (int c = 0; c < 16; ++c) a[c] += f*Wm1[d*16+c];
  }
  float pm[16];
#pragma unroll
  for (int c2 = 0; c2 < 16; ++c2) {
    float t = 0.f;
#pragma unroll
    for (int c = 0; c < 16; ++c) t += fmaxf(a[c], 0.f)*Wm2[c*16+c2];
    pm[c2] = fmaxf(t, 0.f);
  }
  // k=0 smeta gather issued here; latency hides under the pfd matmul
  const float4* mp0 = (const float4*)(smeta + (size_t)((b<<9) + mi0)*20);
  float4 c0 = mp0[0], c1 = mp0[1], c2v = mp0[2], c3 = mp0[3], c4 = mp0[4];
  float pfd[16];
#pragma unroll
  for (int c = 0; c < 16; ++c) pfd[c] = 0.f;
#pragma unroll
  for (int d = 0; d < DD; ++d) {
    float f = pf[d];
#pragma unroll
    for (int c = 0; c < 16; ++c) pfd[c] += f*Wf1[d*16+c];
  }
  float x = xyz[(size_t)i*3+0], y = xyz[(size_t)i*3+1], z = xyz[(size_t)i*3+2];
  float lg[KK];
#pragma unroll 1
  for (int k = 0; k < KK; ++k) {
    // next cluster index: issued at iteration top (k=5 reloads cpb[5]; harmless)
    int mi2 = cpb[(k + 1 < KK) ? (k + 1) : k];
    float wa[16];
    wa[0]=c0.x-pfd[0];  wa[1]=c0.y-pfd[1];  wa[2]=c0.z-pfd[2];  wa[3]=c0.w-pfd[3];
    wa[4]=c1.x-pfd[4];  wa[5]=c1.y-pfd[5];  wa[6]=c1.z-pfd[6];  wa[7]=c1.w-pfd[7];
    wa[8]=c2v.x-pfd[8];  wa[9]=c2v.y-pfd[9];  wa[10]=c2v.z-pfd[10]; wa[11]=c2v.w-pfd[11];
    wa[12]=c3.x-pfd[12]; wa[13]=c3.y-pfd[13]; wa[14]=c3.z-pfd[14]; wa[15]=c3.w-pfd[15];
    float wf[16];
#pragma unroll
    for (int c2 = 0; c2 < 16; ++c2) {
      float t = 0.f;
#pragma unroll
      for (int c = 0; c < 16; ++c) t += fmaxf(wa[c], 0.f)*Wf2[c*16+c2];
      wf[c2] = fmaxf(t, 0.f);
    }
    // prefetch next smeta into named regs; latency hides under ax/lgk below
    const float4* np = (const float4*)(smeta + (size_t)((b<<9) + mi2)*20);
    float4 n0 = np[0], n1 = np[1], n2 = np[2], n3 = np[3], n4 = np[4];
    float dx = c4.x - x, dy = c4.y - y, dz = c4.z - z;
    float ax[16];
#pragma unroll
    for (int c = 0; c < 16; ++c)
      ax[c] = fmaxf(dx*Wx1[c] + dy*Wx1[16+c] + dz*Wx1[32+c], 0.f);
    float lgk = 0.f;
#pragma unroll
    for (int c2 = 0; c2 < 16; ++c2) {
      float t = 0.f;
#pragma unroll
      for (int c = 0; c < 16; ++c) t += ax[c]*Wx2[c*16+c2];
      lgk += fmaxf(t, 0.f)*wf[c2]*pm[c2];
    }
    lg[k] = lgk;
    c0 = n0; c1 = n1; c2v = n2; c3 = n3; c4 = n4;
  }
  float mx = lg[0];
#pragma unroll
  for (int k = 1; k < KK; ++k) mx = fmaxf(mx, lg[k]);
  float e[KK], s = 0.f;
#pragma unroll
  for (int k = 0; k < KK; ++k) { e[k] = expf(lg[k]-mx); s += e[k]; }
#pragma unroll
  for (int k = 0; k < KK; ++k) {
    float wv = e[k]/s;
    wout[(size_t)i*KK+k] = wv;
    if (wout2) wout2[(size_t)i*KK+k] = wv;
  }
}

// ---------------- per-point finalization ----------------
__global__ __launch_bounds__(256) void k_final(const float* __restrict__ sp_xyz, const float* __restrict__ sp_label,
                        const int* __restrict__ c2p, float* __restrict__ out) {
  int i = blockIdx.x*256 + threadIdx.x;
  int b = i >> 13;
  float w[KK]; int id[KK];
#pragma unroll
  for (int k = 0; k < KK; ++k) {
    w[k] = out[O_ASSO + (size_t)i*KK+k];
    id[k] = c2p[(size_t)i*KK+k];
  }
  int best = 0; float bv = w[0];
#pragma unroll
  for (int k = 1; k < KK; ++k) if (w[k] > bv) { bv = w[k]; best = k; }
  int sel = id[best];
#pragma unroll
  for (int c = 0; c < 3; ++c)
    out[O_RPXYZ + (size_t)i*3+c] = sp_xyz[((size_t)b*MM+sel)*3+c];
  float acc[CC];
#pragma unroll
  for (int c = 0; c < CC; ++c) acc[c] = 0.f;
#pragma unroll
  for (int k = 0; k < KK; ++k) {
    const float* sl = sp_label + ((size_t)b*MM + id[k])*CC;
    float ww = w[k];
#pragma unroll
    for (int c = 0; c < CC; ++c) acc[c] += ww*sl[c];
  }
#pragma unroll
  for (int c = 0; c < CC; ++c) out[O_RPLAB + (size_t)i*CC+c] = acc[c];
}

// ---------------- launcher ----------------
extern "C" void kernel_launch(void* const* d_in, const int* in_sizes, int n_in,
                              void* d_out, int out_size, void* d_ws, size_t ws_size,
                              hipStream_t stream) {
  const float* pc     = (const float*)d_in[0];
  const float* knn    = (const float*)d_in[1];
  const float* onehot = (const float*)d_in[2];
  const int*   label  = (const int*)d_in[3];
  const float* Wk1    = (const float*)d_in[4];
  const float* Wk2    = (const float*)d_in[5];
  const float* Wg     = (const float*)d_in[6];
  const float* hW1    = (const float*)d_in[7];
  const float* hW2    = (const float*)d_in[8];
  const float* Wf1    = (const float*)d_in[9];
  const float* Wf2    = (const float*)d_in[10];
  const float* Wx1    = (const float*)d_in[11];
  const float* Wx2    = (const float*)d_in[12];
  const float* Wm1    = (const float*)d_in[13];
  const float* Wm2    = (const float*)d_in[14];
  float* out = (float*)d_out;

  float* wsf = (float*)d_ws;
  size_t o = 0;
  float* xyz     = wsf + o; o += (size_t)BB*NN*3;
  float* cxyz    = wsf + o; o += (size_t)BB*MM*3;
  int*   cidx    = (int*)(wsf + o); o += BB*MM;
  int*   c2p     = (int*)(wsf + o); o += (size_t)BB*NN*KK;
  int*   cnt     = (int*)(wsf + o); o += BB*MM;
  int*   offs    = (int*)(wsf + o); o += BB*MM;
  int*   entries = (int*)(wsf + o); o += (size_t)BB*NN*KK;
  float* sp_fea  = wsf + o; o += (size_t)BB*MM*DD;
  float* sp_xyz  = wsf + o; o += (size_t)BB*MM*3;
  float* sp_label= wsf + o; o += (size_t)BB*MM*CC;
  float* smeta   = wsf + o; o += (size_t)BB*MM*20;

  k_fps  <<<BB, 256, 0, stream>>>(pc, cidx, cxyz, out);
  k_pfea <<<BB*NN/256, 256, 0, stream>>>(pc, knn, Wk1, Wk2, Wg, hW1, hW2, xyz, out);
  k_knn  <<<BB*NN/256, 256, 0, stream>>>(xyz, cxyz, cidx, c2p, out);
  k_csr  <<<BB, 1024, 0, stream>>>(c2p, label, cnt, offs, entries, out);
  // init: sp_fea = mean, sp_xyz = cluster_xyz, smeta for layer 0
  k_scat<<<BB*MM, 256, 0, stream>>>(out + O_PFEA, xyz, nullptr, cxyz, nullptr,
      entries, offs, cnt, Wf1 /*layer0*/, sp_fea, sp_xyz, nullptr, smeta, out);
  for (int l = 0; l < 4; ++l) {
    k_slicw<<<BB*NN/256, 256, 0, stream>>>(out + O_PFEA, xyz, smeta, c2p,
        Wf1 + l*DD*16, Wf2 + l*256, Wx1 + l*48, Wx2 + l*256,
        Wm1 + l*DD*16, Wm2 + l*256,
        out + O_ASSO, (l == 3) ? (out + O_FDIST) : nullptr);
    k_scat<<<BB*MM, 256, 0, stream>>>(out + O_PFEA, xyz, out + O_ASSO, cxyz,
        (l == 3) ? onehot : nullptr, entries, offs, cnt,
        (l < 3) ? (Wf1 + (l+1)*DD*16) : nullptr,
        sp_fea, sp_xyz, sp_label, smeta, out);
  }
  k_final<<<BB*NN/256, 256, 0, stream>>>(sp_xyz, sp_label, c2p, out);
}

// Round 13
// 1505.106 us; speedup vs baseline: 1.0209x; 1.0209x over previous
//
#include <hip/hip_runtime.h>

#define BB 8
#define NN 8192
#define MM 512
#define KK 6
#define NSAMP 16
#define CC 13
#define DD 64

typedef float v2f __attribute__((ext_vector_type(2)));

// ---- output slot offsets (in floats) ----
#define O_ASSO   0u          // final_asso      (B,N,K)  393216
#define O_CIDX   393216u     // cluster_idx     (B,M)    4096
#define O_C2P    397312u     // c2p_idx         (B,N,K)  393216
#define O_C2PA   790528u     // c2p_idx_abs     (B,N,K)  393216
#define O_OUT    1183744u    // out             (B,N,C)  851968
#define O_RPXYZ  2035712u    // re_p_xyz        (B,N,3)  196608
#define O_RPLAB  2232320u    // re_p_label      (B,N,C)  851968
#define O_FDIST  3084288u    // fea_dist        (B,N,K)  393216
#define O_PFEA   3477504u    // p_fea           (B,N,D)  4194304
#define O_SPLABT 7671808u    // sp_label^T      (B,C,M)  53248
#define O_PSLAB  7725056u    // sp_pseudo_lab   (B,M)    4096
#define O_PSOH   7729152u    // sp_pseudo_oh    (B,C,M)  53248

// ---- wave64 DPP max ladders (result valid in lane 63) ----
// f32: bound_ctrl 0-fill is safe (all values >= 0).
__device__ __forceinline__ float wave_max_f32(float v) {
#define FSTEP(ctrl)                                                            \
  {                                                                            \
    int n_ = __builtin_amdgcn_update_dpp(0, __float_as_int(v), ctrl, 0xf, 0xf, \
                                         true);                                \
    v = fmaxf(v, __int_as_float(n_));                                          \
  }
  FSTEP(0x111)  // row_shr:1
  FSTEP(0x112)  // row_shr:2
  FSTEP(0x114)  // row_shr:4
  FSTEP(0x118)  // row_shr:8
  FSTEP(0x142)  // row_bcast:15
  FSTEP(0x143)  // row_bcast:31
#undef FSTEP
  return v;
}
// u32: bound_ctrl 0-fill safe (0 never wins a max of nonzero candidate keys).
__device__ __forceinline__ unsigned wave_max_u32(unsigned v) {
#define USTEP(ctrl)                                                            \
  {                                                                            \
    unsigned n_ =                                                              \
        (unsigned)__builtin_amdgcn_update_dpp(0, (int)v, ctrl, 0xf, 0xf, true);\
    v = (n_ > v) ? n_ : v;                                                     \
  }
  USTEP(0x111) USTEP(0x112) USTEP(0x114) USTEP(0x118) USTEP(0x142) USTEP(0x143)
#undef USTEP
  return v;
}

// ================= FPS: one 256-thread block per batch, 32 pts/thread ============
// STANDALONE kernel — do NOT fuse other work into this kernel (R1 post-mortem:
// shared register allocation poisons the co-resident path; 25x slowdown).
// MEASURED FLOOR ~420us — do not re-probe these refuted directions:
//  R5:  two-barrier selection split  -> +39us (barrier drain > issue saved)
//  R11: 8w->4w issue halving         -> +-0   (step is NOT issue-bound)
//  R12: tree-resolve + u64 ladder    -> +33us (keys+cmp_u64 lengthen chain)
// The step time is pinned by fixed latencies of the inherently serial
// 511-step algorithm: per-step barrier drain/re-arb + two LDS round-trips
// (lane63 key write->read, winner xyz broadcast) + the dist-update chain.
// Selection (bit-exact vs reference, validated across R1-R12):
//  - per-point argmax -> v_pk_max + 16-wide equality-resolve (descending j,
//    B then A: first match = smallest p; same tie rule as original u64 key).
//  - f32 DPP ladder + readlane(63) -> wave max; candidate key
//    (0xFFFFFFFF - p, 0 otherwise) + u32 DPP ladder; lane63 packs u64 into
//    s_best[parity][wave]. ONE barrier; depth-2 u64 tree merge.
// waves_per_eu(1,1) + launch_bounds(256,1): ~128 VGPR of point state must
// stay resident (session failure mode #1). Health check: VGPR >= 130.
__attribute__((amdgpu_waves_per_eu(1, 1)))
__global__ __launch_bounds__(256, 1) void k_fps(const float* __restrict__ pc,
                                                int* __restrict__ cidx,
                                                float* __restrict__ cxyz,
                                                float* __restrict__ out) {
#pragma clang fp contract(off)
  __shared__ float4 sxyzw[NN];                 // 128 KB
  __shared__ unsigned long long s_best[2][4];
  __shared__ int s_pidx[MM];
  const int t = threadIdx.x;                   // 0..255
  const int b = blockIdx.x;
  const float* xb = pc + (size_t)b * NN * 6;
  v2f px[16], py[16], pz[16], dist[16];
#pragma unroll
  for (int j = 0; j < 16; ++j) {
    int p0 = t + (2*j)*256, p1 = t + (2*j+1)*256;
    float X0 = xb[(size_t)p0*6+0], Y0 = xb[(size_t)p0*6+1], Z0 = xb[(size_t)p0*6+2];
    float X1 = xb[(size_t)p1*6+0], Y1 = xb[(size_t)p1*6+1], Z1 = xb[(size_t)p1*6+2];
    px[j] = (v2f){X0, X1}; py[j] = (v2f){Y0, Y1}; pz[j] = (v2f){Z0, Z1};
    dist[j] = (v2f){1e10f, 1e10f};
    sxyzw[p0] = make_float4(X0, Y0, Z0, 0.f);
    sxyzw[p1] = make_float4(X1, Y1, Z1, 0.f);
  }
  __syncthreads();
  float4 cv = sxyzw[0];
  float lx = cv.x, ly = cv.y, lz = cv.z;
  if (t == 0) s_pidx[0] = 0;
  const int lane = t & 63, wave = t >> 6;      // wave 0..3
  for (int step = 1; step < MM; ++step) {
    v2f vmax2 = (v2f){-1.0f, -1.0f};
#pragma unroll
    for (int j = 0; j < 16; ++j) {
      v2f dx = px[j] - lx, dy = py[j] - ly, dz = pz[j] - lz;
      v2f d = (dx*dx + dy*dy) + dz*dz;       // contract(off): exact numpy order
      v2f nd = __builtin_elementwise_min(dist[j], d);
      dist[j] = nd;
      vmax2 = __builtin_elementwise_max(vmax2, nd);
    }
    float vbest = fmaxf(vmax2.x, vmax2.y);
    // smallest (2j+s) with dist == vbest (exact: vbest is one of the values)
    int sel = 0;
#pragma unroll
    for (int j = 15; j >= 0; --j) {
      sel = (dist[j].y == vbest) ? (2*j+1) : sel;
      sel = (dist[j].x == vbest) ? (2*j)   : sel;
    }
    int p_lane = t + (sel << 8);
    float wred = wave_max_f32(vbest);
    float wmax = __int_as_float(
        __builtin_amdgcn_readlane(__float_as_int(wred), 63));
    unsigned cand = (vbest == wmax) ? (0xFFFFFFFFu - (unsigned)p_lane) : 0u;
    unsigned cred = wave_max_u32(cand);
    if (lane == 63)
      s_best[step & 1][wave] =
          ((unsigned long long)__float_as_uint(wmax) << 32) | cred;
    __syncthreads();                      // single barrier (parity dbuf)
    const ulonglong2* sb = (const ulonglong2*)s_best[step & 1];
    ulonglong2 q0 = sb[0], q1 = sb[1];
    unsigned long long m0 = (q0.y > q0.x) ? q0.y : q0.x;   // depth-2 tree
    unsigned long long m1 = (q1.y > q1.x) ? q1.y : q1.x;
    unsigned long long kk = (m1 > m0) ? m1 : m0;
    int p = (int)(0xFFFFFFFFu - (unsigned)(kk & 0xFFFFFFFFull));
    float4 cp = sxyzw[p];                 // one b128 LDS broadcast
    lx = cp.x; ly = cp.y; lz = cp.z;
    if (t == 0) s_pidx[step] = p;
  }
  __syncthreads();
  // coalesced epilogue: 256 threads cover 512 selected entries
  for (int idx = t; idx < MM; idx += 256) {
    int p = s_pidx[idx];
    cidx[b*MM + idx] = p;
    out[O_CIDX + b*MM + idx] = (float)p;
    float4 cc = sxyzw[p];
    cxyz[((size_t)b*MM + idx)*3+0] = cc.x;
    cxyz[((size_t)b*MM + idx)*3+1] = cc.y;
    cxyz[((size_t)b*MM + idx)*3+2] = cc.z;
  }
}

// ================= pack + p_fea + head: 1 point/thread, no LDS ===================
// amdgpu_waves_per_eu(1,2): 256-VGPR budget so acc[64]+h1[32] stay in registers.
// (Do NOT change the attribute; do NOT fuse into k_fps — R1 post-mortem.)
__attribute__((amdgpu_waves_per_eu(1, 2)))
__global__ __launch_bounds__(256) void k_pfea(const float* __restrict__ pc,
                                              const float* __restrict__ knn,
                                              const float* __restrict__ Wk1,
                                              const float* __restrict__ Wk2,
                                              const float* __restrict__ Wg,
                                              const float* __restrict__ hW1,
                                              const float* __restrict__ hW2,
                                              float* __restrict__ xyz,
                                              float* __restrict__ out) {
  int i = blockIdx.x * 256 + threadIdx.x;
  const float2* pr = (const float2*)(pc + (size_t)i*6);
  float2 r0 = pr[0], r1 = pr[1], r2 = pr[2];
  float* xo = xyz + (size_t)i*3;
  xo[0] = r0.x; xo[1] = r0.y; xo[2] = r1.x;
  float acc[DD];
#pragma unroll
  for (int d = 0; d < DD; ++d) acc[d] = -3.4e38f;
  const float* kp = knn + (size_t)i * NSAMP * 2;
  for (int s = 0; s < NSAMP; ++s) {
    float u = kp[s*2+0], v2 = kp[s*2+1];
    float h1[32];
#pragma unroll
    for (int j = 0; j < 32; ++j) h1[j] = fmaxf(u*Wk1[j] + v2*Wk1[32+j], 0.f);
#pragma unroll
    for (int d = 0; d < DD; ++d) {
      float tt = 0.f;
#pragma unroll
      for (int j = 0; j < 32; ++j) tt += h1[j]*Wk2[j*DD+d];
      acc[d] = fmaxf(acc[d], tt);
    }
  }
  float f0 = r1.y, f1 = r2.x, f2 = r2.y;
#pragma unroll
  for (int d = 0; d < DD; ++d) {
    float hg = fmaxf(f0*Wg[d] + f1*Wg[DD+d] + f2*Wg[2*DD+d], 0.f);
    acc[d] = fmaxf(acc[d], 0.f) + hg;          // final p_fea value
    out[O_PFEA + (size_t)i*DD + d] = acc[d];
  }
  // fused head MLP: out = relu(p_fea @ hW1) @ hW2
  float o[CC];
#pragma unroll
  for (int c = 0; c < CC; ++c) o[c] = 0.f;
  for (int d = 0; d < DD; ++d) {
    float t1 = 0.f;
#pragma unroll
    for (int j = 0; j < DD; ++j) t1 += acc[j]*hW1[j*DD+d];
    t1 = fmaxf(t1, 0.f);
#pragma unroll
    for (int c = 0; c < CC; ++c) o[c] += t1*hW2[d*CC+c];
  }
#pragma unroll
  for (int c = 0; c < CC; ++c) out[O_OUT + (size_t)i*CC + c] = o[c];
}

// ---------------- 6-NN cluster search (stable top-k) ----------------
__global__ __launch_bounds__(256) void k_knn(const float* __restrict__ xyz,
                      const float* __restrict__ cxyz,
                      const int* __restrict__ cidx, int* __restrict__ c2p,
                      float* __restrict__ out) {
  __shared__ float4 sc[MM];
  int i = blockIdx.x * 256 + threadIdx.x;
  int b = i >> 13;
  for (int m = threadIdx.x; m < MM; m += 256) {
    sc[m] = make_float4(cxyz[((size_t)b*MM+m)*3+0], cxyz[((size_t)b*MM+m)*3+1],
                        cxyz[((size_t)b*MM+m)*3+2], 0.f);
  }
  __syncthreads();
  float x = xyz[(size_t)i*3+0], y = xyz[(size_t)i*3+1], z = xyz[(size_t)i*3+2];
  float dv[KK]; int di[KK];
#pragma unroll
  for (int j = 0; j < KK; ++j) { dv[j] = 3.4e38f; di[j] = 0; }
  for (int m = 0; m < MM; ++m) {
    float4 c = sc[m];
    float dx = x - c.x, dy = y - c.y, dz = z - c.z;
    float d = __fadd_rn(__fadd_rn(__fmul_rn(dx,dx), __fmul_rn(dy,dy)), __fmul_rn(dz,dz));
    if (d < dv[KK-1]) {
      float v = d; int vi = m; bool ins = false;
#pragma unroll
      for (int j = 0; j < KK; ++j) {
        bool doit = ins || (v < dv[j]);   // strict <: stable top_k
        float tv = doit ? dv[j] : v; int ti = doit ? di[j] : vi;
        if (doit) { dv[j] = v; di[j] = vi; }
        v = tv; vi = ti; ins = doit;
      }
    }
  }
#pragma unroll
  for (int k = 0; k < KK; ++k) {
    c2p[(size_t)i*KK+k] = di[k];
    out[O_C2PA + (size_t)i*KK + k] = (float)di[k];
    out[O_C2P  + (size_t)i*KK + k] = (float)cidx[b*MM + di[k]];
  }
}

// ---------------- fused CSR build + pseudo-label: one block per batch ----------
// R7 post-mortem: global-atomic CSR split (knn-fused count + scan + fill) was
// neutral (+14us) — this single-kernel form is equal or better and simpler.
__global__ __launch_bounds__(1024) void k_csr(const int* __restrict__ c2p,
                                              const int* __restrict__ label,
                                              int* __restrict__ cnt_g,
                                              int* __restrict__ offs_g,
                                              int* __restrict__ entries,
                                              float* __restrict__ out) {
  __shared__ int s_cnt[MM];
  __shared__ int s_off[MM];
  __shared__ int s_cur[MM];
  __shared__ int s_lab[MM*CC];
  int b = blockIdx.x, t = threadIdx.x;
  for (int i = t; i < MM; i += 1024) s_cnt[i] = 0;
  for (int i = t; i < MM*CC; i += 1024) s_lab[i] = 0;
  __syncthreads();
  const int* cb = c2p + (size_t)b*NN*KK;
  const int* lb = label + (size_t)b*NN;
  for (int n = t; n < NN; n += 1024) {
    int lab = lb[n];
#pragma unroll
    for (int k = 0; k < KK; ++k) {
      int m = cb[(size_t)n*KK+k];
      atomicAdd(&s_cnt[m], 1);
      atomicAdd(&s_lab[m*CC+lab], 1);
    }
  }
  __syncthreads();
  if (t < MM) s_off[t] = s_cnt[t];
  __syncthreads();
  for (int off = 1; off < MM; off <<= 1) {
    int v = 0;
    if (t < MM && t >= off) v = s_off[t-off];
    __syncthreads();
    if (t < MM && t >= off) s_off[t] += v;
    __syncthreads();
  }
  if (t < MM) {
    int ex = (t == 0) ? 0 : s_off[t-1];
    s_cur[t] = ex;
    offs_g[b*MM+t] = ex;
    cnt_g[b*MM+t] = s_cnt[t];
    int best = 0, bv = s_lab[t*CC];
#pragma unroll
    for (int c = 1; c < CC; ++c) { int v = s_lab[t*CC+c]; if (v > bv) { bv = v; best = c; } }
    out[O_PSLAB + b*MM + t] = (float)best;
#pragma unroll
    for (int c = 0; c < CC; ++c)
      out[O_PSOH + ((size_t)b*CC + c)*MM + t] = (c == best) ? 1.0f : 0.0f;
  }
  __syncthreads();
  for (int n = t; n < NN; n += 1024) {
#pragma unroll
    for (int k = 0; k < KK; ++k) {
      int m = cb[(size_t)n*KK+k];
      int pos = atomicAdd(&s_cur[m], 1);
      entries[(size_t)b*NN*KK + pos] = n*KK + k;
    }
  }
}

// ---------------- weighted scatter + fused sf@Wf1 (smeta) ----------------
// w==null     : init mode (w=1, sp_xyz=cxyz, den floor 1.0)
// onehot!=null: also produce sp_label (+ transposed output)
// Wf1n!=null  : produce smeta for the NEXT slic layer
// R5/R6 (measured ~-40us total): 2-deep load pipeline — entry e+4's loads
// issue before entry e is accumulated. Same FP order (bit-identical).
__global__ __launch_bounds__(256, 1) void k_scat(const float* __restrict__ pfea,
                          const float* __restrict__ xyz,
                          const float* __restrict__ w,
                          const float* __restrict__ cxyz,
                          const float* __restrict__ onehot,
                          const int* __restrict__ entries, const int* __restrict__ offs,
                          const int* __restrict__ cnt,
                          const float* __restrict__ Wf1n,
                          float* __restrict__ sp_fea, float* __restrict__ sp_xyz,
                          float* __restrict__ sp_label, float* __restrict__ smeta,
                          float* __restrict__ out) {
  int bm = blockIdx.x;
  int b = bm >> 9, m = bm & (MM-1);
  int t = threadIdx.x;
  int wv = t >> 6, lane = t & 63;
  int base = b*NN*KK;
  int st = offs[bm], n_e = cnt[bm];
  __shared__ int   s_ent[1024];
  __shared__ float s_w[1024];
  __shared__ float s_f[4][DD], s_x[4][4], s_l[4][16], s_d[4];
  __shared__ float s_sf[DD], s_part[16][17];
  float acc = 0.f, accx = 0.f, accl = 0.f, den = 0.f;
  for (int c0 = 0; c0 < n_e; c0 += 1024) {
    int cn = min(1024, n_e - c0);
    __syncthreads();
    for (int e = t; e < cn; e += 256) {
      int ee = entries[base + st + c0 + e];
      s_ent[e] = ee;
      s_w[e] = w ? w[(size_t)base + ee] : 1.0f;
    }
    __syncthreads();
    int e = wv;
    if (e < cn) {
      int ee = s_ent[e];
      float ww = s_w[e];
      int n = ee / KK;
      float pv = pfea[((size_t)b*NN+n)*DD + lane];
      float xv = (lane < 3) ? xyz[((size_t)b*NN+n)*3 + lane] : 0.f;
      float ov = (onehot && lane < CC) ? onehot[((size_t)b*NN+n)*CC + lane] : 0.f;
      for (; e + 4 < cn; e += 4) {
        int ee2 = s_ent[e+4];
        float ww2 = s_w[e+4];
        int n2 = ee2 / KK;
        float pv2 = pfea[((size_t)b*NN+n2)*DD + lane];
        float xv2 = (lane < 3) ? xyz[((size_t)b*NN+n2)*3 + lane] : 0.f;
        float ov2 = (onehot && lane < CC) ? onehot[((size_t)b*NN+n2)*CC + lane] : 0.f;
        acc += ww * pv;
        if (lane < 3) accx += ww * xv;
        if (onehot && lane < CC) accl += ww * ov;
        den += ww;
        ww = ww2; pv = pv2; xv = xv2; ov = ov2;
      }
      acc += ww * pv;
      if (lane < 3) accx += ww * xv;
      if (onehot && lane < CC) accl += ww * ov;
      den += ww;
    }
  }
  s_f[wv][lane] = acc;
  if (lane < 4)  s_x[wv][lane] = (lane < 3) ? accx : 0.f;
  if (lane < 16) s_l[wv][lane] = (lane < CC) ? accl : 0.f;
  if (lane == 0) s_d[wv] = den;
  __syncthreads();
  if (wv == 0) {
    float A  = s_f[0][lane] + s_f[1][lane] + s_f[2][lane] + s_f[3][lane];
    float Dn = s_d[0] + s_d[1] + s_d[2] + s_d[3];
    float dv = w ? fmaxf(Dn, 1e-8f) : fmaxf(Dn, 1.0f);
    float sfv = A / dv;
    sp_fea[(size_t)bm*DD + lane] = sfv;
    s_sf[lane] = sfv;
    if (lane < 3) {
      float X = w ? (s_x[0][lane]+s_x[1][lane]+s_x[2][lane]+s_x[3][lane]) / dv
                  : cxyz[bm*3+lane];
      sp_xyz[bm*3+lane] = X;
      if (Wf1n) smeta[bm*20 + 16 + lane] = X;
    }
    if (onehot && lane < CC) {
      float L = (s_l[0][lane]+s_l[1][lane]+s_l[2][lane]+s_l[3][lane]) / fmaxf(Dn, 1e-8f);
      sp_label[(size_t)bm*CC + lane] = L;
      out[O_SPLABT + ((size_t)b*CC + lane)*MM + m] = L;
    }
  }
  if (Wf1n) {
    __syncthreads();
    int c = t & 15, part = t >> 4;
    float pr = 0.f;
#pragma unroll
    for (int q = 0; q < 4; ++q)
      pr += s_sf[part*4+q] * Wf1n[(part*4+q)*16 + c];
    s_part[part][c] = pr;
    __syncthreads();
    if (t < 16) {
      float sm = 0.f;
#pragma unroll
      for (int q = 0; q < 16; ++q) sm += s_part[q][t];
      smeta[bm*20 + t] = sm;
    }
  }
}

// ---------------- SLIC weight computation (one iteration) ----------------
// (1,2): 256-VGPR budget; pf[64] + pipeline regs stay resident.
// R2 post-mortem: keep `#pragma unroll 1` on the k-loop (full unroll collapsed
// the allocation to 88 VGPR, pf[64] evicted, 5.5x slower at 1 wave/EU).
// R8 post-mortem: half-split 2x-TLP regressed (barriers + duplicated work).
// R9 post-mortem: LDS-staging smeta regressed (smeta is L2-resident; the
// rolled prefetch below already hides the gather latency; staging exposed it).
// R4 rolled-loop software pipeline (measured best): prologue hoists c2p[0] +
// k=0 smeta gather under the a/pm/pfd matmuls; each iteration issues c2p[k+1]
// at top and the next smeta gather mid-iteration into NAMED regs n0..n4
// (static indexing only), rotated at the bottom.
__attribute__((amdgpu_waves_per_eu(1, 2)))
__global__ __launch_bounds__(256) void k_slicw(const float* __restrict__ pfea,
                        const float* __restrict__ xyz,
                        const float* __restrict__ smeta,
                        const int* __restrict__ c2p,
                        const float* __restrict__ Wf1, const float* __restrict__ Wf2,
                        const float* __restrict__ Wx1, const float* __restrict__ Wx2,
                        const float* __restrict__ Wm1, const float* __restrict__ Wm2,
                        float* __restrict__ wout, float* __restrict__ wout2) {
  int i = blockIdx.x*256 + threadIdx.x;
  int b = i >> 13;
  const int* cpb = c2p + (size_t)i*KK;
  int mi0 = cpb[0];                       // issued early; hidden under a/pm
  float pf[DD];
  const float4* pf4 = (const float4*)(pfea + (size_t)i*DD);
#pragma unroll
  for (int q = 0; q < DD/4; ++q) {
    float4 t = pf4[q];
    pf[q*4+0] = t.x; pf[q*4+1] = t.y; pf[q*4+2] = t.z; pf[q*4+3] = t.w;
  }
  float a[16];
#pragma unroll
  for (int c = 0; c < 16; ++c) a[c] = 0.f;
#pragma unroll
  for (int d = 0; d < DD; ++d) {
    float f = pf[d];
#pragma unroll
    for (int c = 0; c < 16; ++c) a[c] += f*Wm1[d*16+c];
  }
  float pm[16];
#pragma unroll
  for (int c2 = 0; c2 < 16; ++c2) {
    float t = 0.f;
#pragma unroll
    for (int c = 0; c < 16; ++c) t += fmaxf(a[c], 0.f)*Wm2[c*16+c2];
    pm[c2] = fmaxf(t, 0.f);
  }
  // k=0 smeta gather issued here; latency hides under the pfd matmul
  const float4* mp0 = (const float4*)(smeta + (size_t)((b<<9) + mi0)*20);
  float4 c0 = mp0[0], c1 = mp0[1], c2v = mp0[2], c3 = mp0[3], c4 = mp0[4];
  float pfd[16];
#pragma unroll
  for (int c = 0; c < 16; ++c) pfd[c] = 0.f;
#pragma unroll
  for (int d = 0; d < DD; ++d) {
    float f = pf[d];
#pragma unroll
    for (int c = 0; c < 16; ++c) pfd[c] += f*Wf1[d*16+c];
  }
  float x = xyz[(size_t)i*3+0], y = xyz[(size_t)i*3+1], z = xyz[(size_t)i*3+2];
  float lg[KK];
#pragma unroll 1
  for (int k = 0; k < KK; ++k) {
    // next cluster index: issued at iteration top (k=5 reloads cpb[5]; harmless)
    int mi2 = cpb[(k + 1 < KK) ? (k + 1) : k];
    float wa[16];
    wa[0]=c0.x-pfd[0];  wa[1]=c0.y-pfd[1];  wa[2]=c0.z-pfd[2];  wa[3]=c0.w-pfd[3];
    wa[4]=c1.x-pfd[4];  wa[5]=c1.y-pfd[5];  wa[6]=c1.z-pfd[6];  wa[7]=c1.w-pfd[7];
    wa[8]=c2v.x-pfd[8];  wa[9]=c2v.y-pfd[9];  wa[10]=c2v.z-pfd[10]; wa[11]=c2v.w-pfd[11];
    wa[12]=c3.x-pfd[12]; wa[13]=c3.y-pfd[13]; wa[14]=c3.z-pfd[14]; wa[15]=c3.w-pfd[15];
    float wf[16];
#pragma unroll
    for (int c2 = 0; c2 < 16; ++c2) {
      float t = 0.f;
#pragma unroll
      for (int c = 0; c < 16; ++c) t += fmaxf(wa[c], 0.f)*Wf2[c*16+c2];
      wf[c2] = fmaxf(t, 0.f);
    }
    // prefetch next smeta into named regs; latency hides under ax/lgk below
    const float4* np = (const float4*)(smeta + (size_t)((b<<9) + mi2)*20);
    float4 n0 = np[0], n1 = np[1], n2 = np[2], n3 = np[3], n4 = np[4];
    float dx = c4.x - x, dy = c4.y - y, dz = c4.z - z;
    float ax[16];
#pragma unroll
    for (int c = 0; c < 16; ++c)
      ax[c] = fmaxf(dx*Wx1[c] + dy*Wx1[16+c] + dz*Wx1[32+c], 0.f);
    float lgk = 0.f;
#pragma unroll
    for (int c2 = 0; c2 < 16; ++c2) {
      float t = 0.f;
#pragma unroll
      for (int c = 0; c < 16; ++c) t += ax[c]*Wx2[c*16+c2];
      lgk += fmaxf(t, 0.f)*wf[c2]*pm[c2];
    }
    lg[k] = lgk;
    c0 = n0; c1 = n1; c2v = n2; c3 = n3; c4 = n4;
  }
  float mx = lg[0];
#pragma unroll
  for (int k = 1; k < KK; ++k) mx = fmaxf(mx, lg[k]);
  float e[KK], s = 0.f;
#pragma unroll
  for (int k = 0; k < KK; ++k) { e[k] = expf(lg[k]-mx); s += e[k]; }
#pragma unroll
  for (int k = 0; k < KK; ++k) {
    float wv = e[k]/s;
    wout[(size_t)i*KK+k] = wv;
    if (wout2) wout2[(size_t)i*KK+k] = wv;
  }
}

// ---------------- per-point finalization ----------------
__global__ __launch_bounds__(256) void k_final(const float* __restrict__ sp_xyz, const float* __restrict__ sp_label,
                        const int* __restrict__ c2p, float* __restrict__ out) {
  int i = blockIdx.x*256 + threadIdx.x;
  int b = i >> 13;
  float w[KK]; int id[KK];
#pragma unroll
  for (int k = 0; k < KK; ++k) {
    w[k] = out[O_ASSO + (size_t)i*KK+k];
    id[k] = c2p[(size_t)i*KK+k];
  }
  int best = 0; float bv = w[0];
#pragma unroll
  for (int k = 1; k < KK; ++k) if (w[k] > bv) { bv = w[k]; best = k; }
  int sel = id[best];
#pragma unroll
  for (int c = 0; c < 3; ++c)
    out[O_RPXYZ + (size_t)i*3+c] = sp_xyz[((size_t)b*MM+sel)*3+c];
  float acc[CC];
#pragma unroll
  for (int c = 0; c < CC; ++c) acc[c] = 0.f;
#pragma unroll
  for (int k = 0; k < KK; ++k) {
    const float* sl = sp_label + ((size_t)b*MM + id[k])*CC;
    float ww = w[k];
#pragma unroll
    for (int c = 0; c < CC; ++c) acc[c] += ww*sl[c];
  }
#pragma unroll
  for (int c = 0; c < CC; ++c) out[O_RPLAB + (size_t)i*CC+c] = acc[c];
}

// ---------------- launcher ----------------
extern "C" void kernel_launch(void* const* d_in, const int* in_sizes, int n_in,
                              void* d_out, int out_size, void* d_ws, size_t ws_size,
                              hipStream_t stream) {
  const float* pc     = (const float*)d_in[0];
  const float* knn    = (const float*)d_in[1];
  const float* onehot = (const float*)d_in[2];
  const int*   label  = (const int*)d_in[3];
  const float* Wk1    = (const float*)d_in[4];
  const float* Wk2    = (const float*)d_in[5];
  const float* Wg     = (const float*)d_in[6];
  const float* hW1    = (const float*)d_in[7];
  const float* hW2    = (const float*)d_in[8];
  const float* Wf1    = (const float*)d_in[9];
  const float* Wf2    = (const float*)d_in[10];
  const float* Wx1    = (const float*)d_in[11];
  const float* Wx2    = (const float*)d_in[12];
  const float* Wm1    = (const float*)d_in[13];
  const float* Wm2    = (const float*)d_in[14];
  float* out = (float*)d_out;

  float* wsf = (float*)d_ws;
  size_t o = 0;
  float* xyz     = wsf + o; o += (size_t)BB*NN*3;
  float* cxyz    = wsf + o; o += (size_t)BB*MM*3;
  int*   cidx    = (int*)(wsf + o); o += BB*MM;
  int*   c2p     = (int*)(wsf + o); o += (size_t)BB*NN*KK;
  int*   cnt     = (int*)(wsf + o); o += BB*MM;
  int*   offs    = (int*)(wsf + o); o += BB*MM;
  int*   entries = (int*)(wsf + o); o += (size_t)BB*NN*KK;
  float* sp_fea  = wsf + o; o += (size_t)BB*MM*DD;
  float* sp_xyz  = wsf + o; o += (size_t)BB*MM*3;
  float* sp_label= wsf + o; o += (size_t)BB*MM*CC;
  float* smeta   = wsf + o; o += (size_t)BB*MM*20;

  k_fps  <<<BB, 256, 0, stream>>>(pc, cidx, cxyz, out);
  k_pfea <<<BB*NN/256, 256, 0, stream>>>(pc, knn, Wk1, Wk2, Wg, hW1, hW2, xyz, out);
  k_knn  <<<BB*NN/256, 256, 0, stream>>>(xyz, cxyz, cidx, c2p, out);
  k_csr  <<<BB, 1024, 0, stream>>>(c2p, label, cnt, offs, entries, out);
  // init: sp_fea = mean, sp_xyz = cluster_xyz, smeta for layer 0
  k_scat<<<BB*MM, 256, 0, stream>>>(out + O_PFEA, xyz, nullptr, cxyz, nullptr,
      entries, offs, cnt, Wf1 /*layer0*/, sp_fea, sp_xyz, nullptr, smeta, out);
  for (int l = 0; l < 4; ++l) {
    k_slicw<<<BB*NN/256, 256, 0, stream>>>(out + O_PFEA, xyz, smeta, c2p,
        Wf1 + l*DD*16, Wf2 + l*256, Wx1 + l*48, Wx2 + l*256,
        Wm1 + l*DD*16, Wm2 + l*256,
        out + O_ASSO, (l == 3) ? (out + O_FDIST) : nullptr);
    k_scat<<<BB*MM, 256, 0, stream>>>(out + O_PFEA, xyz, out + O_ASSO, cxyz,
        (l == 3) ? onehot : nullptr, entries, offs, cnt,
        (l < 3) ? (Wf1 + (l+1)*DD*16) : nullptr,
        sp_fea, sp_xyz, sp_label, smeta, out);
  }
  k_final<<<BB*NN/256, 256, 0, stream>>>(sp_xyz, sp_label, c2p, out);
}